// Round 1
// baseline (39.821 us; speedup 1.0000x reference)
//
#include <hip/hip_runtime.h>
#include <math.h>

// Problem constants
#define NB 64     // batches
#define NM 8      // rx dims
#define NK 4      // tx dims (digits)
#define NP 16     // constellation points
#define NV 65536  // candidate vectors

// ws layout (float offsets)
#define WS_YW   0        // [64][8][2]          = 1024 floats
#define WS_HW   1024     // [64][8][4][2]       = 4096 floats
#define WS_GMAX 5120     // uint keys [64][64]  = 4096
#define WS_GSUM 9216     // double [64][64]     = 8192 floats worth (32KB, 8B aligned: 9216*4=36864 ok)

__device__ __forceinline__ unsigned enc_f(float f) {
    unsigned u = __float_as_uint(f);
    return (u & 0x80000000u) ? ~u : (u | 0x80000000u);
}
__device__ __forceinline__ float dec_f(unsigned k) {
    unsigned u = (k & 0x80000000u) ? (k ^ 0x80000000u) : ~k;
    return __uint_as_float(u);
}

// ---------------- K1: per-batch Cholesky + forward solves + ws init ----------------
__global__ void k_whiten(const float* __restrict__ yr, const float* __restrict__ yi,
                         const float* __restrict__ hr, const float* __restrict__ hi,
                         const float* __restrict__ sr, const float* __restrict__ si,
                         float* __restrict__ ws) {
    int t = threadIdx.x;  // 64 threads, one batch each
    unsigned* gk = (unsigned*)(ws + WS_GMAX);
    for (int i = t; i < 4096; i += 64) gk[i] = 0u;          // key(-inf) > 0, so 0 == "empty"
    double* gs = (double*)(ws + WS_GSUM);
    for (int i = t; i < 4096; i += 64) gs[i] = 0.0;
    int b = t;
    float Lr[8][8], Li[8][8], Dinv[8];
    const float* srb = sr + b * 64;
    const float* sib = si + b * 64;
#pragma unroll
    for (int j = 0; j < 8; ++j) {
        float d = srb[j * 8 + j];
#pragma unroll
        for (int k = 0; k < 8; ++k) if (k < j) d -= Lr[j][k] * Lr[j][k] + Li[j][k] * Li[j][k];
        float ld = sqrtf(d);
        float inv = 1.f / ld;
        Dinv[j] = inv;
        Lr[j][j] = ld; Li[j][j] = 0.f;
#pragma unroll
        for (int i = 0; i < 8; ++i) if (i > j) {
            float cr = srb[i * 8 + j], ci = sib[i * 8 + j];
#pragma unroll
            for (int k = 0; k < 8; ++k) if (k < j) {
                cr -= Lr[i][k] * Lr[j][k] + Li[i][k] * Li[j][k];
                ci -= Li[i][k] * Lr[j][k] - Lr[i][k] * Li[j][k];
            }
            Lr[i][j] = cr * inv;
            Li[i][j] = ci * inv;
        }
    }
    // yw = L^{-1} y
    float zr[8], zi[8];
#pragma unroll
    for (int i = 0; i < 8; ++i) {
        float cr = yr[b * 8 + i], ci = yi[b * 8 + i];
#pragma unroll
        for (int k = 0; k < 8; ++k) if (k < i) {
            cr -= Lr[i][k] * zr[k] - Li[i][k] * zi[k];
            ci -= Lr[i][k] * zi[k] + Li[i][k] * zr[k];
        }
        zr[i] = cr * Dinv[i]; zi[i] = ci * Dinv[i];
        ws[WS_YW + (b * 8 + i) * 2] = zr[i];
        ws[WS_YW + (b * 8 + i) * 2 + 1] = zi[i];
    }
    // hw[:,c] = L^{-1} h[:,c]
#pragma unroll
    for (int c = 0; c < 4; ++c) {
#pragma unroll
        for (int i = 0; i < 8; ++i) {
            float cr = hr[(b * 8 + i) * 4 + c], ci = hi[(b * 8 + i) * 4 + c];
#pragma unroll
            for (int k = 0; k < 8; ++k) if (k < i) {
                cr -= Lr[i][k] * zr[k] - Li[i][k] * zi[k];
                ci -= Lr[i][k] * zi[k] + Li[i][k] * zr[k];
            }
            zr[i] = cr * Dinv[i]; zi[i] = ci * Dinv[i];
            ws[WS_HW + ((b * 8 + i) * 4 + c) * 2] = zr[i];
            ws[WS_HW + ((b * 8 + i) * 4 + c) * 2 + 1] = zi[i];
        }
    }
}

// Shared prelude for the V-scan kernels: build tab[k][p][m] = hw[b][m][k]*pts[p]
// pts[p] read from vecs at v = p<<12, k=0 (digit0 of that v is p, others 0... actually
// vecs[p<<12][0] = pts[p] exactly since idx[p<<12,0] = p).
#define BUILD_TAB()                                                            \
    for (int e = t; e < 512; e += 256) {                                       \
        int k = e >> 7, p = (e >> 3) & 15, m = e & 7;                          \
        float hre = ws[WS_HW + ((b * 8 + m) * 4 + k) * 2];                     \
        float him = ws[WS_HW + ((b * 8 + m) * 4 + k) * 2 + 1];                 \
        float pr = vr[(p << 12) * 4];                                          \
        float pim = vi[(p << 12) * 4];                                         \
        tab[k][p][m][0] = hre * pr - him * pim;                                \
        tab[k][p][m][1] = hre * pim + him * pr;                                \
    }

#define BUILD_BASE()                                                           \
    int i3 = t & 15, i2 = t >> 4;                                              \
    float br[8], bi[8];                                                        \
    _Pragma("unroll")                                                          \
    for (int m = 0; m < 8; ++m) {                                              \
        br[m] = tab[0][chunk][m][0] + tab[2][i2][m][0] + tab[3][i3][m][0]      \
                - ws[WS_YW + (b * 8 + m) * 2];                                 \
        bi[m] = tab[0][chunk][m][1] + tab[2][i2][m][1] + tab[3][i3][m][1]      \
                - ws[WS_YW + (b * 8 + m) * 2 + 1];                             \
    }

// ---------------- K2a: per-group maxes (atomicMax on ordered keys) ----------------
__global__ __launch_bounds__(256) void k_maxes(const float* __restrict__ vr,
                                               const float* __restrict__ vi,
                                               float* __restrict__ ws) {
    __shared__ float tab[4][16][8][2];
    __shared__ float xbuf[4096];
    __shared__ float part[256];
    __shared__ float res[64];
    int bid = blockIdx.x;
    int b = bid >> 4, chunk = bid & 15;
    int t = threadIdx.x;
    BUILD_TAB();
    __syncthreads();
    BUILD_BASE();
#pragma unroll
    for (int s = 0; s < 16; ++s) {
        float acc = 0.f;
#pragma unroll
        for (int m = 0; m < 8; ++m) {
            float dr = br[m] + tab[1][s][m][0];
            float di = bi[m] + tab[1][s][m][1];
            acc += dr * dr + di * di;
        }
        xbuf[s * 256 + t] = -acc;   // local index e = s*256+t; digits: d1=s d2=t>>4 d3=t&15
    }
    __syncthreads();
    // j=1 groups: e>>8 == p  (contiguous 256 runs)
    {
        float v = xbuf[(t >> 4) * 256 + (t & 15) * 16];
#pragma unroll
        for (int lo = 1; lo < 16; ++lo) v = fmaxf(v, xbuf[(t >> 4) * 256 + (t & 15) * 16 + lo]);
        part[t] = v;
    }
    __syncthreads();
    if (t < 16) {
        float v = part[t * 16];
        for (int i = 1; i < 16; ++i) v = fmaxf(v, part[t * 16 + i]);
        res[16 + t] = v;
    }
    __syncthreads();
    // j=2 groups: (e>>4)&15 == p
    {
        float v = xbuf[(t & 15) * 256 + (t >> 4) * 16];
#pragma unroll
        for (int lo = 1; lo < 16; ++lo) v = fmaxf(v, xbuf[(t & 15) * 256 + (t >> 4) * 16 + lo]);
        part[t] = v;
    }
    __syncthreads();
    if (t < 16) {
        float v = part[t * 16];
        for (int i = 1; i < 16; ++i) v = fmaxf(v, part[t * 16 + i]);
        res[32 + t] = v;
    }
    __syncthreads();
    // j=3 groups: e&15 == p
    {
        float v = xbuf[(t >> 4) * 16 + (t & 15)];
#pragma unroll
        for (int i = 1; i < 16; ++i) v = fmaxf(v, xbuf[((t >> 4) + 16 * i) * 16 + (t & 15)]);
        part[t] = v;
    }
    __syncthreads();
    if (t < 16) {
        float v = part[t];
        for (int i = 1; i < 16; ++i) v = fmaxf(v, part[t + 16 * i]);
        res[48 + t] = v;
    }
    __syncthreads();
    // j=0 group for this chunk: max over everything = max of the 16 j3-group maxes
    if (t == 0) {
        float v = res[48];
        for (int i = 1; i < 16; ++i) v = fmaxf(v, res[48 + i]);
        res[chunk] = v;
    }
    __syncthreads();
    unsigned* gk = (unsigned*)(ws + WS_GMAX);
    if (t >= 16 && t < 64) atomicMax(&gk[b * 64 + t], enc_f(res[t]));
    if (t == 0) atomicMax(&gk[b * 64 + chunk], enc_f(res[chunk]));
}

// ---------------- K2b: per-group sums of exp(x - m_g) (recompute x) ----------------
__global__ __launch_bounds__(256) void k_sums(const float* __restrict__ vr,
                                              const float* __restrict__ vi,
                                              float* __restrict__ ws) {
    __shared__ float tab[4][16][8][2];
    __shared__ float xbuf[4096];
    __shared__ float part[256];
    __shared__ float res[64];
    __shared__ float s0[16];
    int bid = blockIdx.x;
    int b = bid >> 4, chunk = bid & 15;
    int t = threadIdx.x;
    BUILD_TAB();
    __syncthreads();
    BUILD_BASE();
    const unsigned* gk = (const unsigned*)(ws + WS_GMAX);
    float m0 = dec_f(gk[b * 64 + chunk]);
    float m2 = dec_f(gk[b * 64 + 32 + i2]);
    float m3 = dec_f(gk[b * 64 + 48 + i3]);
    float acc0 = 0.f, acc2 = 0.f, acc3 = 0.f;
#pragma unroll
    for (int s = 0; s < 16; ++s) {
        float acc = 0.f;
#pragma unroll
        for (int m = 0; m < 8; ++m) {
            float dr = br[m] + tab[1][s][m][0];
            float di = bi[m] + tab[1][s][m][1];
            acc += dr * dr + di * di;
        }
        float x = -acc;
        acc0 += __expf(x - m0);
        acc2 += __expf(x - m2);
        acc3 += __expf(x - m3);
        float m1s = dec_f(gk[b * 64 + 16 + s]);
        xbuf[s * 256 + t] = __expf(x - m1s);
    }
    __syncthreads();
    // j=1 sums: sum 256 consecutive per s
    {
        float v = 0.f;
#pragma unroll
        for (int lo = 0; lo < 16; ++lo) v += xbuf[(t >> 4) * 256 + (t & 15) * 16 + lo];
        part[t] = v;
    }
    __syncthreads();
    if (t < 16) {
        float v = 0.f;
        for (int i = 0; i < 16; ++i) v += part[t * 16 + i];
        res[16 + t] = v;
    }
    __syncthreads();
    // j=2 sums: acc2 over threads with t>>4 == p
    part[t] = acc2;
    __syncthreads();
    if (t < 16) {
        float v = 0.f;
        for (int i = 0; i < 16; ++i) v += part[t * 16 + i];
        res[32 + t] = v;
    }
    __syncthreads();
    // j=3 sums: acc3 over threads with t&15 == p
    part[t] = acc3;
    __syncthreads();
    if (t < 16) {
        float v = 0.f;
        for (int i = 0; i < 16; ++i) v += part[t + 16 * i];
        res[48 + t] = v;
    }
    __syncthreads();
    // j=0 sum: acc0 over all threads
    part[t] = acc0;
    __syncthreads();
    if (t < 16) {
        float v = 0.f;
        for (int i = 0; i < 16; ++i) v += part[t + 16 * i];
        s0[t] = v;
    }
    __syncthreads();
    double* gs = (double*)(ws + WS_GSUM);
    if (t >= 16 && t < 64) atomicAdd(&gs[b * 64 + t], (double)res[t]);
    if (t == 0) {
        float v = 0.f;
        for (int i = 0; i < 16; ++i) v += s0[i];
        atomicAdd(&gs[b * 64 + chunk], (double)v);
    }
}

// ---------------- K2c: logits = log(sum) + max ----------------
__global__ void k_final(const float* __restrict__ ws, float* __restrict__ out) {
    int idx = blockIdx.x * 256 + threadIdx.x;  // 4096 outputs: [b][j][p]
    int b = idx >> 6, g = idx & 63;
    const unsigned* gk = (const unsigned*)(ws + WS_GMAX);
    const double* gs = (const double*)(ws + WS_GSUM);
    out[idx] = logf((float)gs[b * 64 + g]) + dec_f(gk[b * 64 + g]);
}

extern "C" void kernel_launch(void* const* d_in, const int* in_sizes, int n_in,
                              void* d_out, int out_size, void* d_ws, size_t ws_size,
                              hipStream_t stream) {
    const float* yr = (const float*)d_in[0];
    const float* yi = (const float*)d_in[1];
    const float* hr = (const float*)d_in[2];
    const float* hi = (const float*)d_in[3];
    const float* sr = (const float*)d_in[4];
    const float* si = (const float*)d_in[5];
    const float* vr = (const float*)d_in[6];
    const float* vi = (const float*)d_in[7];
    float* ws = (float*)d_ws;
    float* out = (float*)d_out;
    hipLaunchKernelGGL(k_whiten, dim3(1), dim3(64), 0, stream, yr, yi, hr, hi, sr, si, ws);
    hipLaunchKernelGGL(k_maxes, dim3(1024), dim3(256), 0, stream, vr, vi, ws);
    hipLaunchKernelGGL(k_sums, dim3(1024), dim3(256), 0, stream, vr, vi, ws);
    hipLaunchKernelGGL(k_final, dim3(16), dim3(256), 0, stream, ws, out);
}

// Round 2
// 20.360 us; speedup vs baseline: 1.9559x; 1.9559x over previous
//
#include <hip/hip_runtime.h>
#include <math.h>

// B=64, M=8, K=4, P=16, V=65536. Block = (batch b, chunk = digit0 value).
// Grid 1024 = 64 b x 16 chunks, 256 threads.
// Groups g = j*16+p. j=0 group == one block (finalized in-block).
// j=1..3: block writes (local max, local sum) per group to ws; k_comb merges.

__global__ __launch_bounds__(256) void k_main(
    const float* __restrict__ yr, const float* __restrict__ yi,
    const float* __restrict__ hr, const float* __restrict__ hi,
    const float* __restrict__ sr, const float* __restrict__ si,
    const float* __restrict__ vr, const float* __restrict__ vi,
    float* __restrict__ ws, float* __restrict__ out)
{
    __shared__ float sL[8][8][2];    // Cholesky factor rows
    __shared__ float sDinv[8];
    __shared__ float lyw[8][2];      // whitened y
    __shared__ float lhw[8][4][2];   // whitened h [m][k]
    __shared__ float tab[4][16][8][2]; // hw[m][k]*pts[p]
    __shared__ float xbuf[16][256];  // exponents, [d1][d2*16+d3]
    __shared__ float pA[256], pB[256], pC[256];
    __shared__ float lmax[48];       // local group maxes: j1 p | j2 p | j3 p
    __shared__ float gsum[48];       // local group sums

    const int t = threadIdx.x;
    const int bid = blockIdx.x;
    const int b = bid >> 4, chunk = bid & 15;

    // ---------- whiten: 8-thread cooperative complex Cholesky ----------
    float Lr_[8], Li_[8], a_r[8], a_i[8];
    if (t < 8) {
#pragma unroll
        for (int k = 0; k < 8; ++k) {
            a_r[k] = sr[b * 64 + t * 8 + k];
            a_i[k] = si[b * 64 + t * 8 + k];
        }
    }
#pragma unroll
    for (int j = 0; j < 8; ++j) {
        if (t == j) {
            float d = a_r[j];
#pragma unroll
            for (int k = 0; k < 8; ++k) if (k < j) d -= Lr_[k]*Lr_[k] + Li_[k]*Li_[k];
            float ld = sqrtf(d);
            Lr_[j] = ld; Li_[j] = 0.f;
            sDinv[j] = 1.f / ld;
#pragma unroll
            for (int k = 0; k < 8; ++k) if (k <= j) { sL[j][k][0] = Lr_[k]; sL[j][k][1] = Li_[k]; }
        }
        __syncthreads();
        if (t < 8 && t > j) {
            float cr = a_r[j], ci = a_i[j];
#pragma unroll
            for (int k = 0; k < 8; ++k) if (k < j) {
                cr -= Lr_[k]*sL[j][k][0] + Li_[k]*sL[j][k][1];
                ci -= Li_[k]*sL[j][k][0] - Lr_[k]*sL[j][k][1];
            }
            float inv = sDinv[j];
            Lr_[j] = cr * inv; Li_[j] = ci * inv;
        }
    }
    // 5 independent forward solves: t==0 -> y, t==1..4 -> h column t-1
    if (t < 5) {
        float rr[8], ri[8], zr[8], zi[8];
        if (t == 0) {
#pragma unroll
            for (int i = 0; i < 8; ++i) { rr[i] = yr[b*8+i]; ri[i] = yi[b*8+i]; }
        } else {
#pragma unroll
            for (int i = 0; i < 8; ++i) { rr[i] = hr[(b*8+i)*4 + (t-1)]; ri[i] = hi[(b*8+i)*4 + (t-1)]; }
        }
#pragma unroll
        for (int i = 0; i < 8; ++i) {
            float cr = rr[i], ci = ri[i];
#pragma unroll
            for (int k = 0; k < 8; ++k) if (k < i) {
                cr -= sL[i][k][0]*zr[k] - sL[i][k][1]*zi[k];
                ci -= sL[i][k][0]*zi[k] + sL[i][k][1]*zr[k];
            }
            float inv = sDinv[i];
            zr[i] = cr * inv; zi[i] = ci * inv;
            if (t == 0) { lyw[i][0] = zr[i]; lyw[i][1] = zi[i]; }
            else        { lhw[i][t-1][0] = zr[i]; lhw[i][t-1][1] = zi[i]; }
        }
    }
    __syncthreads();

    // ---------- tab[k][p][m] = hw[m][k] * pts[p]  (pts read from vecs[p<<12][0]) ----------
    for (int e = t; e < 512; e += 256) {
        int k = e >> 7, p = (e >> 3) & 15, m = e & 7;
        float hre = lhw[m][k][0], him = lhw[m][k][1];
        float pr = vr[(p << 12) * 4], pim = vi[(p << 12) * 4];
        tab[k][p][m][0] = hre*pr - him*pim;
        tab[k][p][m][1] = hre*pim + him*pr;
    }
    __syncthreads();

    // ---------- x for all 4096 candidates of this chunk ----------
    const int i3 = t & 15, i2 = t >> 4;
    float br[8], bi[8];
#pragma unroll
    for (int m = 0; m < 8; ++m) {
        br[m] = tab[0][chunk][m][0] + tab[2][i2][m][0] + tab[3][i3][m][0] - lyw[m][0];
        bi[m] = tab[0][chunk][m][1] + tab[2][i2][m][1] + tab[3][i3][m][1] - lyw[m][1];
    }
#pragma unroll
    for (int s = 0; s < 16; ++s) {
        float acc = 0.f;
#pragma unroll
        for (int m = 0; m < 8; ++m) {
            float dr = br[m] + tab[1][s][m][0];
            float di = bi[m] + tab[1][s][m][1];
            acc += dr*dr + di*di;
        }
        xbuf[s][t] = -acc;   // element (d1=s, d2=t>>4, d3=t&15)
    }
    __syncthreads();

    // ---------- block-local group maxes ----------
    // loop A: thread column (fixed d2,d3) over d1 -> feeds j2/j3 reductions
    float vmA = xbuf[0][t];
#pragma unroll
    for (int s = 1; s < 16; ++s) vmA = fmaxf(vmA, xbuf[s][t]);
    pA[t] = vmA;
    // loop B: thread = (d1 group = t>>4, d3 = t&15) over d2 -> feeds j1 reduction
    float vmB = xbuf[i2][i3];
#pragma unroll
    for (int d2 = 1; d2 < 16; ++d2) vmB = fmaxf(vmB, xbuf[i2][d2*16 + i3]);
    pB[t] = vmB;
    __syncthreads();
    if (t < 16) {
        float v1 = pB[t*16], v2 = pA[t*16], v3 = pA[t];
#pragma unroll
        for (int i = 1; i < 16; ++i) {
            v1 = fmaxf(v1, pB[t*16 + i]);   // j1 group p=t (d1==t)
            v2 = fmaxf(v2, pA[t*16 + i]);   // j2 group p=t (d2==t)
            v3 = fmaxf(v3, pA[t + 16*i]);   // j3 group p=t (d3==t)
        }
        lmax[t] = v1; lmax[16+t] = v2; lmax[32+t] = v3;
    }
    __syncthreads();

    // ---------- block-local group sums ----------
    const float M1 = lmax[i2];        // loop-B thread's j1 group is s=t>>4
    const float M2 = lmax[16 + i2];
    const float M3 = lmax[32 + i3];
    float acc1 = 0.f, acc2 = 0.f, acc3 = 0.f;
#pragma unroll
    for (int s = 0; s < 16; ++s) {
        float v = xbuf[s][t];
        acc2 += __expf(v - M2);
        acc3 += __expf(v - M3);
    }
#pragma unroll
    for (int d2 = 0; d2 < 16; ++d2) {
        float w = xbuf[i2][d2*16 + i3];
        acc1 += __expf(w - M1);
    }
    pA[t] = acc2; pB[t] = acc3; pC[t] = acc1;
    __syncthreads();
    if (t < 16) {
        float s1 = 0.f, s2 = 0.f, s3 = 0.f;
#pragma unroll
        for (int i = 0; i < 16; ++i) {
            s1 += pC[t*16 + i];
            s2 += pA[t*16 + i];
            s3 += pB[t + 16*i];
        }
        gsum[t] = s1; gsum[16+t] = s2; gsum[32+t] = s3;
    }
    __syncthreads();

    // ---------- emit: 48 (m,s) pairs + the finalized j0 logit ----------
    if (t < 48) {
        float* w = ws + ((b*48 + t)*16 + chunk)*2;
        w[0] = lmax[t];
        w[1] = gsum[t];
    }
    if (t == 0) {
        // j0 group (this whole block) = exact LSE-merge of the 16 j2 locals
        float M = lmax[16];
#pragma unroll
        for (int i = 1; i < 16; ++i) M = fmaxf(M, lmax[16+i]);
        float S = 0.f;
#pragma unroll
        for (int i = 0; i < 16; ++i) S += gsum[16+i] * __expf(lmax[16+i] - M);
        out[b*64 + chunk] = logf(S) + M;
    }
}

// ---------- merge the 16 chunk-local (m,s) pairs per group ----------
__global__ __launch_bounds__(256) void k_comb(const float* __restrict__ ws, float* __restrict__ out)
{
    int idx = blockIdx.x * 256 + threadIdx.x;
    if (idx >= 64 * 48) return;
    int b = idx / 48, gi = idx % 48;
    const float* p = ws + (b*48 + gi)*32;
    float M = p[0];
#pragma unroll
    for (int i = 1; i < 16; ++i) M = fmaxf(M, p[2*i]);
    float S = 0.f;
#pragma unroll
    for (int i = 0; i < 16; ++i) S += p[2*i+1] * __expf(p[2*i] - M);
    out[b*64 + 16 + gi] = logf(S) + M;
}

extern "C" void kernel_launch(void* const* d_in, const int* in_sizes, int n_in,
                              void* d_out, int out_size, void* d_ws, size_t ws_size,
                              hipStream_t stream) {
    const float* yr = (const float*)d_in[0];
    const float* yi = (const float*)d_in[1];
    const float* hr = (const float*)d_in[2];
    const float* hi = (const float*)d_in[3];
    const float* sr = (const float*)d_in[4];
    const float* si = (const float*)d_in[5];
    const float* vr = (const float*)d_in[6];
    const float* vi = (const float*)d_in[7];
    float* ws = (float*)d_ws;
    float* out = (float*)d_out;
    hipLaunchKernelGGL(k_main, dim3(1024), dim3(256), 0, stream,
                       yr, yi, hr, hi, sr, si, vr, vi, ws, out);
    hipLaunchKernelGGL(k_comb, dim3(12), dim3(256), 0, stream, ws, out);
}